// Round 1
// baseline (858.104 us; speedup 1.0000x reference)
//
#include <hip/hip_runtime.h>
#include <hip/hip_bf16.h>

// MFMA fragment types (16x16x32 bf16: verified layouts m89/m120)
typedef __attribute__((ext_vector_type(8))) short bf16x8;
typedef __attribute__((ext_vector_type(4))) float f32x4;

static __device__ __forceinline__ short f2bf(float f) {
  union { float f; unsigned u; } v; v.f = f;
  unsigned r = v.u + 0x7fffu + ((v.u >> 16) & 1u);   // RNE
  return (short)(r >> 16);
}
static __device__ __forceinline__ float bf2f(short s) {
  union { unsigned u; float f; } v;
  v.u = ((unsigned)(unsigned short)s) << 16;
  return v.f;
}
static __device__ __forceinline__ bf16x8 load8_f32_as_bf16(const float* p) {
  float4 a = *(const float4*)p;
  float4 b = *(const float4*)(p + 4);
  bf16x8 r;
  r[0] = f2bf(a.x); r[1] = f2bf(a.y); r[2] = f2bf(a.z); r[3] = f2bf(a.w);
  r[4] = f2bf(b.x); r[5] = f2bf(b.y); r[6] = f2bf(b.z); r[7] = f2bf(b.w);
  return r;
}

// ---------------------------------------------------------------------------
// A1: WqT[e][d] = bf16(Wq[d][e])   (so B-frag reads of KW GEMM are contiguous)
__global__ void ta_wqt_kernel(const float* __restrict__ Wq, short* __restrict__ WqT) {
  int e = blockIdx.x;
  int d = threadIdx.x;
  WqT[e * 256 + d] = f2bf(Wq[d * 256 + e]);
}

// ---------------------------------------------------------------------------
// A2: k = task @ Wk^T + bk  -> k_bf[b][m][d] (bf16)
//     v = task @ Wv^T + bv  -> vT_bf[b][d][m] (bf16, transposed via LDS)
__global__ __launch_bounds__(256) void ta_kv_kernel(
    const float* __restrict__ task, const float* __restrict__ Wk,
    const float* __restrict__ bk, const float* __restrict__ Wv,
    const float* __restrict__ bv, short* __restrict__ k_bf,
    short* __restrict__ vT_bf)
{
  __shared__ __align__(16) short buf_t[256 * 72];   // v tile transposed [d][m_local]
  const int b = blockIdx.y, mt = blockIdx.x;
  const int tid = threadIdx.x;
  const int w = tid >> 6, lane = tid & 63, l16 = lane & 15, quad = lane >> 4;
  const int mbase = mt * 64;

  // A-frags of task rows (wave-private 16 rows), A[m=lane&15][k=quad*8+j]
  bf16x8 afrag[8];
  const float* trow = task + (size_t)(b * 256 + mbase + w * 16 + l16) * 256;
#pragma unroll
  for (int ks = 0; ks < 8; ++ks)
    afrag[ks] = load8_f32_as_bf16(trow + ks * 32 + quad * 8);

  // ---- k projection
#pragma unroll
  for (int t = 0; t < 16; ++t) {
    f32x4 acc = {0.f, 0.f, 0.f, 0.f};
#pragma unroll
    for (int ks = 0; ks < 8; ++ks) {
      // B[k=e][n=d] = Wk[d][e]: row d of Wk, contiguous e  (X@W^T pattern)
      bf16x8 bfr = load8_f32_as_bf16(Wk + (t * 16 + l16) * 256 + ks * 32 + quad * 8);
      acc = __builtin_amdgcn_mfma_f32_16x16x32_bf16(afrag[ks], bfr, acc, 0, 0, 0);
    }
    float bias = bk[t * 16 + l16];
#pragma unroll
    for (int r = 0; r < 4; ++r) {
      int m = mbase + w * 16 + quad * 4 + r;       // C: row=quad*4+reg, col=lane&15
      k_bf[(b * 256 + m) * 256 + t * 16 + l16] = f2bf(acc[r] + bias);
    }
  }

  // ---- v projection -> LDS transpose
#pragma unroll
  for (int t = 0; t < 16; ++t) {
    f32x4 acc = {0.f, 0.f, 0.f, 0.f};
#pragma unroll
    for (int ks = 0; ks < 8; ++ks) {
      bf16x8 bfr = load8_f32_as_bf16(Wv + (t * 16 + l16) * 256 + ks * 32 + quad * 8);
      acc = __builtin_amdgcn_mfma_f32_16x16x32_bf16(afrag[ks], bfr, acc, 0, 0, 0);
    }
    float bias = bv[t * 16 + l16];
#pragma unroll
    for (int r = 0; r < 4; ++r) {
      int d = t * 16 + l16;
      int ml = w * 16 + quad * 4 + r;
      buf_t[d * 72 + ml] = f2bf(acc[r] + bias);
    }
  }
  __syncthreads();
  // coalesced store of vT[b][d][mbase..mbase+63]
#pragma unroll
  for (int it = 0; it < 8; ++it) {
    int d = it * 32 + (tid >> 3);
    int c = tid & 7;
    *(bf16x8*)&vT_bf[(b * 256 + d) * 256 + mbase + c * 8] =
        *(const bf16x8*)&buf_t[d * 72 + c * 8];
  }
}

// ---------------------------------------------------------------------------
// A3: KWs[b][m][e] = ((k @ Wq)[m][e]) / 16  (bf16);  sbias[b][m] = (bq . k[m])/16
__global__ __launch_bounds__(256) void ta_kw_kernel(
    const short* __restrict__ k_bf, const short* __restrict__ WqT,
    const float* __restrict__ bq, short* __restrict__ KWs,
    float* __restrict__ sbias)
{
  const int b = blockIdx.y, mt = blockIdx.x;
  const int tid = threadIdx.x;
  const int w = tid >> 6, lane = tid & 63, l16 = lane & 15, quad = lane >> 4;
  const int mbase = mt * 64;

  bf16x8 afrag[8];
  const short* krow = k_bf + (size_t)(b * 256 + mbase + w * 16 + l16) * 256;
#pragma unroll
  for (int ks = 0; ks < 8; ++ks)
    afrag[ks] = *(const bf16x8*)(krow + ks * 32 + quad * 8);

#pragma unroll
  for (int t = 0; t < 16; ++t) {
    f32x4 acc = {0.f, 0.f, 0.f, 0.f};
#pragma unroll
    for (int ks = 0; ks < 8; ++ks) {
      // B[k=d][n=e] = Wq[d][e] = WqT[e][d]: row e of WqT, contiguous d
      bf16x8 bfr = *(const bf16x8*)(WqT + (t * 16 + l16) * 256 + ks * 32 + quad * 8);
      acc = __builtin_amdgcn_mfma_f32_16x16x32_bf16(afrag[ks], bfr, acc, 0, 0, 0);
    }
#pragma unroll
    for (int r = 0; r < 4; ++r) {
      int m = mbase + w * 16 + quad * 4 + r;
      KWs[(b * 256 + m) * 256 + t * 16 + l16] = f2bf(acc[r] * 0.0625f);
    }
  }

  if (tid < 64) {
    int m = mbase + tid;
    const short* kr = k_bf + (size_t)(b * 256 + m) * 256;
    float s = 0.f;
    for (int d = 0; d < 256; ++d) s += bq[d] * bf2f(kr[d]);
    sbias[b * 256 + m] = s * 0.0625f;
  }
}

// ---------------------------------------------------------------------------
// B: fused   out[b][n][d] = sum_m sigmoid(x.KWs[m] + sbias[m]) * v[m][d] + x[n][d]
// 64 image rows / block, 4 waves x 16 rows, M chunked by 64.
__global__ __launch_bounds__(256, 3) void ta_attn_kernel(
    const float* __restrict__ x, const short* __restrict__ KWs,
    const short* __restrict__ vT, const float* __restrict__ sbias,
    float* __restrict__ out)
{
  // buf_b time-shared: x-stage [64][264] -> KW chunk [64][264] -> vT chunk [256][72]
  __shared__ __align__(16) short buf_b[256 * 72];     // 36864 B
  __shared__ __align__(16) short buf_p[4][16 * 72];   // 9216 B, wave-private P tiles
  __shared__ float sb_lds[64];
  const int b = blockIdx.y, nt = blockIdx.x;
  const int tid = threadIdx.x;
  const int w = tid >> 6, lane = tid & 63, l16 = lane & 15, quad = lane >> 4;

  const float* xg = x + (size_t)(b * 16384 + nt * 64) * 256;

  // phase 0: stage x tile -> bf16 LDS [64][264] (coalesced float4 reads)
#pragma unroll
  for (int it = 0; it < 16; ++it) {
    int idx = it * 256 + tid;
    int row = idx >> 6, c4 = idx & 63;
    float4 v = *(const float4*)(xg + row * 256 + c4 * 4);
    ushort4 s4;
    s4.x = (unsigned short)f2bf(v.x);
    s4.y = (unsigned short)f2bf(v.y);
    s4.z = (unsigned short)f2bf(v.z);
    s4.w = (unsigned short)f2bf(v.w);
    *(ushort4*)&buf_b[row * 264 + c4 * 4] = s4;
  }
  __syncthreads();

  // x A-frags resident in registers for all chunks (32 VGPR)
  bf16x8 xfrag[8];
#pragma unroll
  for (int ks = 0; ks < 8; ++ks)
    xfrag[ks] = *(const bf16x8*)&buf_b[(w * 16 + l16) * 264 + ks * 32 + quad * 8];

  // output accumulator initialized with the residual (C-layout)
  f32x4 acc[16];
#pragma unroll
  for (int t = 0; t < 16; ++t)
#pragma unroll
    for (int r = 0; r < 4; ++r)
      acc[t][r] = bf2f(buf_b[(w * 16 + quad * 4 + r) * 264 + t * 16 + l16]);
  __syncthreads();

  for (int mc = 0; mc < 256; mc += 64) {
    // stage KW chunk [64][264]
    const short* kwg = KWs + (size_t)(b * 256 + mc) * 256;
#pragma unroll
    for (int it = 0; it < 8; ++it) {
      int idx = it * 256 + tid;
      int row = idx >> 5, c = idx & 31;
      *(bf16x8*)&buf_b[row * 264 + c * 8] = *(const bf16x8*)(kwg + row * 256 + c * 8);
    }
    if (tid < 64) sb_lds[tid] = sbias[b * 256 + mc + tid];
    __syncthreads();

    // S = x @ KW^T (+ sbias), rows=n (wave-private 16), cols=m (64)
    f32x4 sc[4];
#pragma unroll
    for (int t = 0; t < 4; ++t) {
      float sb = sb_lds[t * 16 + l16];
      sc[t][0] = sb; sc[t][1] = sb; sc[t][2] = sb; sc[t][3] = sb;
    }
#pragma unroll
    for (int ks = 0; ks < 8; ++ks) {
#pragma unroll
      for (int t = 0; t < 4; ++t) {
        bf16x8 bfr = *(const bf16x8*)&buf_b[(t * 16 + l16) * 264 + ks * 32 + quad * 8];
        sc[t] = __builtin_amdgcn_mfma_f32_16x16x32_bf16(xfrag[ks], bfr, sc[t], 0, 0, 0);
      }
    }

    // sigmoid, C-layout -> A-layout via wave-private LDS
#pragma unroll
    for (int t = 0; t < 4; ++t)
#pragma unroll
      for (int r = 0; r < 4; ++r) {
        float p = __builtin_amdgcn_rcpf(1.0f + __expf(-sc[t][r]));
        buf_p[w][(quad * 4 + r) * 72 + t * 16 + l16] = f2bf(p);
      }
    bf16x8 pfrag[2];
#pragma unroll
    for (int h = 0; h < 2; ++h)
      pfrag[h] = *(const bf16x8*)&buf_p[w][l16 * 72 + h * 32 + quad * 8];
    __syncthreads();   // all waves done reading KW chunk

    // stage vT chunk [256][72]
    const short* vtg = vT + (size_t)b * 65536 + mc;
#pragma unroll
    for (int it = 0; it < 8; ++it) {
      int idx = it * 256 + tid;
      int row = idx >> 3, c = idx & 7;
      *(bf16x8*)&buf_b[row * 72 + c * 8] = *(const bf16x8*)(vtg + row * 256 + c * 8);
    }
    __syncthreads();

    // out += P @ V : B[k=m][n=d] = vT[d][m]
#pragma unroll
    for (int h = 0; h < 2; ++h)
#pragma unroll
      for (int t = 0; t < 16; ++t) {
        bf16x8 bfr = *(const bf16x8*)&buf_b[(t * 16 + l16) * 72 + h * 32 + quad * 8];
        acc[t] = __builtin_amdgcn_mfma_f32_16x16x32_bf16(pfrag[h], bfr, acc[t], 0, 0, 0);
      }
    __syncthreads();   // protect buf_b for next chunk's staging
  }

  float* og = out + (size_t)(b * 16384 + nt * 64) * 256;
#pragma unroll
  for (int t = 0; t < 16; ++t)
#pragma unroll
    for (int r = 0; r < 4; ++r)
      og[(w * 16 + quad * 4 + r) * 256 + t * 16 + l16] = acc[t][r];
}

// ---------------------------------------------------------------------------
extern "C" void kernel_launch(void* const* d_in, const int* in_sizes, int n_in,
                              void* d_out, int out_size, void* d_ws, size_t ws_size,
                              hipStream_t stream) {
  const float* task  = (const float*)d_in[0];
  const float* image = (const float*)d_in[1];
  const float* Wq    = (const float*)d_in[2];
  const float* bq    = (const float*)d_in[3];
  const float* Wk    = (const float*)d_in[4];
  const float* bk    = (const float*)d_in[5];
  const float* Wv    = (const float*)d_in[6];
  const float* bv    = (const float*)d_in[7];
  float* out = (float*)d_out;

  char* ws = (char*)d_ws;
  short* k_bf  = (short*)(ws);                                   // 2 MiB
  short* KWs   = (short*)(ws + (size_t)(2 << 20));               // 2 MiB
  short* vTb   = (short*)(ws + (size_t)(4 << 20));               // 2 MiB
  short* WqT   = (short*)(ws + (size_t)(6 << 20));               // 128 KiB
  float* sbias = (float*)(ws + (size_t)(6 << 20) + 256 * 256 * 2); // 16 KiB

  ta_wqt_kernel<<<dim3(256), dim3(256), 0, stream>>>(Wq, WqT);
  ta_kv_kernel<<<dim3(4, 16), dim3(256), 0, stream>>>(task, Wk, bk, Wv, bv, k_bf, vTb);
  ta_kw_kernel<<<dim3(4, 16), dim3(256), 0, stream>>>(k_bf, WqT, bq, KWs, sbias);
  ta_attn_kernel<<<dim3(256, 16), dim3(256), 0, stream>>>(image, KWs, vTb, sbias, out);
}

// Round 2
// 649.862 us; speedup vs baseline: 1.3204x; 1.3204x over previous
//
#include <hip/hip_runtime.h>
#include <hip/hip_bf16.h>

// MFMA fragment types (16x16x32 bf16: verified layouts m89/m120)
typedef __attribute__((ext_vector_type(8))) short bf16x8;
typedef __attribute__((ext_vector_type(4))) float f32x4;

static __device__ __forceinline__ short f2bf(float f) {
  union { float f; unsigned u; } v; v.f = f;
  unsigned r = v.u + 0x7fffu + ((v.u >> 16) & 1u);   // RNE
  return (short)(r >> 16);
}
static __device__ __forceinline__ float bf2f(short s) {
  union { unsigned u; float f; } v;
  v.u = ((unsigned)(unsigned short)s) << 16;
  return v.f;
}
static __device__ __forceinline__ bf16x8 load8_f32_as_bf16(const float* p) {
  float4 a = *(const float4*)p;
  float4 b = *(const float4*)(p + 4);
  bf16x8 r;
  r[0] = f2bf(a.x); r[1] = f2bf(a.y); r[2] = f2bf(a.z); r[3] = f2bf(a.w);
  r[4] = f2bf(b.x); r[5] = f2bf(b.y); r[6] = f2bf(b.z); r[7] = f2bf(b.w);
  return r;
}
// async global->LDS, 16B per lane, dest = uniform base + lane*16
static __device__ __forceinline__ void gl2lds16(void* lds, const void* g) {
  __builtin_amdgcn_global_load_lds(
      (const __attribute__((address_space(1))) unsigned int*)g,
      (__attribute__((address_space(3))) unsigned int*)lds, 16, 0, 0);
}

// ---------------------------------------------------------------------------
// A1: WqT[e][d] = bf16(Wq[d][e])  — LDS-tiled 64x64 transpose, coalesced both sides
__global__ __launch_bounds__(256) void ta_wqt_kernel(const float* __restrict__ Wq,
                                                     short* __restrict__ WqT) {
  __shared__ short tile[64 * 72];
  const int et = blockIdx.x, dt = blockIdx.y;
  const int tid = threadIdx.x;
  const int r = tid >> 2, cq = tid & 3;      // 64 rows x 4 col-quarters
#pragma unroll
  for (int q = 0; q < 4; ++q) {
    float4 v = *(const float4*)&Wq[(dt * 64 + r) * 256 + et * 64 + cq * 16 + q * 4];
    tile[(cq * 16 + q * 4 + 0) * 72 + r] = f2bf(v.x);
    tile[(cq * 16 + q * 4 + 1) * 72 + r] = f2bf(v.y);
    tile[(cq * 16 + q * 4 + 2) * 72 + r] = f2bf(v.z);
    tile[(cq * 16 + q * 4 + 3) * 72 + r] = f2bf(v.w);
  }
  __syncthreads();
  const int e = tid >> 2, sq = tid & 3;
  *(bf16x8*)&WqT[(et * 64 + e) * 256 + dt * 64 + sq * 16] =
      *(const bf16x8*)&tile[e * 72 + sq * 16];
  *(bf16x8*)&WqT[(et * 64 + e) * 256 + dt * 64 + sq * 16 + 8] =
      *(const bf16x8*)&tile[e * 72 + sq * 16 + 8];
}

// ---------------------------------------------------------------------------
// A2: k = task @ Wk^T + bk -> k_bf[b][m][d];  v = task @ Wv^T + bv -> vT_bf[b][d][m]
// grid (4 mt, 16 b, 4 ts): each block does 4 d-tiles (64 d values) for 64 m rows.
__global__ __launch_bounds__(256) void ta_kv_kernel(
    const float* __restrict__ task, const float* __restrict__ Wk,
    const float* __restrict__ bk, const float* __restrict__ Wv,
    const float* __restrict__ bv, short* __restrict__ k_bf,
    short* __restrict__ vT_bf)
{
  __shared__ __align__(16) short buf_t[64 * 72];
  const int mt = blockIdx.x, b = blockIdx.y, ts = blockIdx.z;
  const int tid = threadIdx.x;
  const int w = tid >> 6, lane = tid & 63, l16 = lane & 15, quad = lane >> 4;
  const int mbase = mt * 64;

  bf16x8 afrag[8];
  const float* trow = task + (size_t)(b * 256 + mbase + w * 16 + l16) * 256;
#pragma unroll
  for (int ks = 0; ks < 8; ++ks)
    afrag[ks] = load8_f32_as_bf16(trow + ks * 32 + quad * 8);

#pragma unroll
  for (int tt = 0; tt < 4; ++tt) {
    const int t = ts * 4 + tt;
    f32x4 acc = {0.f, 0.f, 0.f, 0.f};
#pragma unroll
    for (int ks = 0; ks < 8; ++ks) {
      bf16x8 bfr = load8_f32_as_bf16(Wk + (t * 16 + l16) * 256 + ks * 32 + quad * 8);
      acc = __builtin_amdgcn_mfma_f32_16x16x32_bf16(afrag[ks], bfr, acc, 0, 0, 0);
    }
    float bias = bk[t * 16 + l16];
#pragma unroll
    for (int r = 0; r < 4; ++r) {
      int m = mbase + w * 16 + quad * 4 + r;
      k_bf[(b * 256 + m) * 256 + t * 16 + l16] = f2bf(acc[r] + bias);
    }
  }

#pragma unroll
  for (int tt = 0; tt < 4; ++tt) {
    const int t = ts * 4 + tt;
    f32x4 acc = {0.f, 0.f, 0.f, 0.f};
#pragma unroll
    for (int ks = 0; ks < 8; ++ks) {
      bf16x8 bfr = load8_f32_as_bf16(Wv + (t * 16 + l16) * 256 + ks * 32 + quad * 8);
      acc = __builtin_amdgcn_mfma_f32_16x16x32_bf16(afrag[ks], bfr, acc, 0, 0, 0);
    }
    float bias = bv[t * 16 + l16];
#pragma unroll
    for (int r = 0; r < 4; ++r)
      buf_t[(tt * 16 + l16) * 72 + w * 16 + quad * 4 + r] = f2bf(acc[r] + bias);
  }
  __syncthreads();
#pragma unroll
  for (int it = 0; it < 2; ++it) {
    int dl = it * 32 + (tid >> 3), c = tid & 7;
    *(bf16x8*)&vT_bf[(b * 256 + ts * 64 + dl) * 256 + mbase + c * 8] =
        *(const bf16x8*)&buf_t[dl * 72 + c * 8];
  }
}

// ---------------------------------------------------------------------------
// A3: KWs[b][m][e] = (k @ Wq)[m][e] / 16  (bf16)
__global__ __launch_bounds__(256) void ta_kw_kernel(
    const short* __restrict__ k_bf, const short* __restrict__ WqT,
    short* __restrict__ KWs)
{
  const int mt = blockIdx.x, b = blockIdx.y, ts = blockIdx.z;
  const int tid = threadIdx.x;
  const int w = tid >> 6, lane = tid & 63, l16 = lane & 15, quad = lane >> 4;
  const int mbase = mt * 64;

  bf16x8 afrag[8];
  const short* krow = k_bf + (size_t)(b * 256 + mbase + w * 16 + l16) * 256;
#pragma unroll
  for (int ks = 0; ks < 8; ++ks)
    afrag[ks] = *(const bf16x8*)(krow + ks * 32 + quad * 8);

#pragma unroll
  for (int tt = 0; tt < 4; ++tt) {
    const int t = ts * 4 + tt;
    f32x4 acc = {0.f, 0.f, 0.f, 0.f};
#pragma unroll
    for (int ks = 0; ks < 8; ++ks) {
      bf16x8 bfr = *(const bf16x8*)(WqT + (t * 16 + l16) * 256 + ks * 32 + quad * 8);
      acc = __builtin_amdgcn_mfma_f32_16x16x32_bf16(afrag[ks], bfr, acc, 0, 0, 0);
    }
#pragma unroll
    for (int r = 0; r < 4; ++r) {
      int m = mbase + w * 16 + quad * 4 + r;
      KWs[(b * 256 + m) * 256 + t * 16 + l16] = f2bf(acc[r] * 0.0625f);
    }
  }
}

// ---------------------------------------------------------------------------
// A4: sbias[b][m] = (bq . k[m]) / 16
__global__ __launch_bounds__(256) void ta_sbias_kernel(
    const short* __restrict__ k_bf, const float* __restrict__ bq,
    float* __restrict__ sbias)
{
  const int b = blockIdx.x, m = threadIdx.x;
  const short* kr = k_bf + (size_t)(b * 256 + m) * 256;
  float s = 0.f;
#pragma unroll 8
  for (int d = 0; d < 256; ++d) s += bq[d] * bf2f(kr[d]);
  sbias[b * 256 + m] = s * 0.0625f;
}

// ---------------------------------------------------------------------------
// B: fused  out[n][d] = sum_m sigmoid(x.KWs[m] + sbias[m]) * v[m][d] + x[n][d]
// 64 n-rows/block, 4 waves x 16 rows, M in 4 chunks of 64.
// Co-resident unpadded KW+vT buffers staged by global_load_lds (linear, no pad);
// 2 barriers/chunk, prefetch issued right after consume-barrier. buf_p is
// wave-private (no barrier). x read directly from global (frags + epilogue).
__global__ __launch_bounds__(256, 2) void ta_attn_kernel(
    const float* __restrict__ x, const short* __restrict__ KWs,
    const short* __restrict__ vT, const float* __restrict__ sbias,
    float* __restrict__ out)
{
  __shared__ __align__(16) short bufKW[64 * 256];    // 32 KB [m_local][e]
  __shared__ __align__(16) short bufVT[256 * 64];    // 32 KB [d][m_local]
  __shared__ __align__(16) short buf_p[4][16 * 72];  // 9 KB wave-private P tiles
  const int b = blockIdx.y, nt = blockIdx.x;
  const int tid = threadIdx.x;
  const int w = tid >> 6, lane = tid & 63, l16 = lane & 15, quad = lane >> 4;

  const float* xg = x + (size_t)(b * 16384 + nt * 64) * 256;
  const short* kwg = KWs + (size_t)b * 65536;
  const short* vtg = vT + (size_t)b * 65536;

  // x A-frags direct from global (16 rows/wave), A[m=l16][k=quad*8+j]
  bf16x8 xfrag[8];
  const float* xrow = xg + (w * 16 + l16) * 256;
#pragma unroll
  for (int ks = 0; ks < 8; ++ks)
    xfrag[ks] = load8_f32_as_bf16(xrow + ks * 32 + quad * 8);

  f32x4 acc[16];
#pragma unroll
  for (int t = 0; t < 16; ++t) { acc[t][0]=0.f; acc[t][1]=0.f; acc[t][2]=0.f; acc[t][3]=0.f; }

  // stage chunk 0 (each wave: 8 KB of KW + 8 KB of vT, 16B/lane linear)
#pragma unroll
  for (int i = 0; i < 8; ++i)
    gl2lds16(&bufKW[w * 4096 + i * 512], kwg + w * 4096 + i * 512 + lane * 8);
#pragma unroll
  for (int i = 0; i < 8; ++i)
    gl2lds16(&bufVT[(w * 64 + i * 8) * 64],
             vtg + (w * 64 + i * 8 + (lane >> 3)) * 256 + (lane & 7) * 8);

  for (int mc = 0; mc < 256; mc += 64) {
    __syncthreads();   // staging of chunk mc visible; prev consumers done

    // S = x @ KW^T (+ sbias), wave rows n = w*16+l16, cols m = 0..63
    f32x4 sc[4];
#pragma unroll
    for (int t = 0; t < 4; ++t) {
      float sb = sbias[b * 256 + mc + t * 16 + l16];
      sc[t][0]=sb; sc[t][1]=sb; sc[t][2]=sb; sc[t][3]=sb;
    }
#pragma unroll
    for (int ks = 0; ks < 8; ++ks)
#pragma unroll
      for (int t = 0; t < 4; ++t) {
        bf16x8 bfr = *(const bf16x8*)&bufKW[(t * 16 + l16) * 256 + ks * 32 + quad * 8];
        sc[t] = __builtin_amdgcn_mfma_f32_16x16x32_bf16(xfrag[ks], bfr, sc[t], 0, 0, 0);
      }

    // sigmoid; C-layout -> A-layout via wave-private LDS (no barrier)
#pragma unroll
    for (int t = 0; t < 4; ++t)
#pragma unroll
      for (int r = 0; r < 4; ++r) {
        float p = __builtin_amdgcn_rcpf(1.0f + __expf(-sc[t][r]));
        buf_p[w][(quad * 4 + r) * 72 + t * 16 + l16] = f2bf(p);
      }
    bf16x8 pfrag[2];
#pragma unroll
    for (int h = 0; h < 2; ++h)
      pfrag[h] = *(const bf16x8*)&buf_p[w][l16 * 72 + h * 32 + quad * 8];

    // out += P @ V :  B[k=m][n=d] = vT[d][m]
#pragma unroll
    for (int h = 0; h < 2; ++h)
#pragma unroll
      for (int t = 0; t < 16; ++t) {
        bf16x8 bfr = *(const bf16x8*)&bufVT[(t * 16 + l16) * 64 + h * 32 + quad * 8];
        acc[t] = __builtin_amdgcn_mfma_f32_16x16x32_bf16(pfrag[h], bfr, acc[t], 0, 0, 0);
      }

    __syncthreads();   // all waves done reading bufKW/bufVT
    if (mc < 192) {    // prefetch next chunk (lands before next top-barrier)
      const short* kwc = kwg + (mc + 64) * 256;
#pragma unroll
      for (int i = 0; i < 8; ++i)
        gl2lds16(&bufKW[w * 4096 + i * 512], kwc + w * 4096 + i * 512 + lane * 8);
#pragma unroll
      for (int i = 0; i < 8; ++i)
        gl2lds16(&bufVT[(w * 64 + i * 8) * 64],
                 vtg + (w * 64 + i * 8 + (lane >> 3)) * 256 + (mc + 64) + (lane & 7) * 8);
    }
  }

  // epilogue: residual + store (C-layout: row=quad*4+r, col=t*16+l16)
  float* og = out + (size_t)(b * 16384 + nt * 64) * 256;
#pragma unroll
  for (int t = 0; t < 16; ++t)
#pragma unroll
    for (int r = 0; r < 4; ++r) {
      int idx = (w * 16 + quad * 4 + r) * 256 + t * 16 + l16;
      og[idx] = acc[t][r] + xg[idx];
    }
}

// ---------------------------------------------------------------------------
extern "C" void kernel_launch(void* const* d_in, const int* in_sizes, int n_in,
                              void* d_out, int out_size, void* d_ws, size_t ws_size,
                              hipStream_t stream) {
  const float* task  = (const float*)d_in[0];
  const float* image = (const float*)d_in[1];
  const float* Wq    = (const float*)d_in[2];
  const float* bq    = (const float*)d_in[3];
  const float* Wk    = (const float*)d_in[4];
  const float* bk    = (const float*)d_in[5];
  const float* Wv    = (const float*)d_in[6];
  const float* bv    = (const float*)d_in[7];
  float* out = (float*)d_out;

  char* ws = (char*)d_ws;
  short* k_bf  = (short*)(ws);                                     // 2 MiB
  short* KWs   = (short*)(ws + (size_t)(2 << 20));                 // 2 MiB
  short* vTb   = (short*)(ws + (size_t)(4 << 20));                 // 2 MiB
  short* WqT   = (short*)(ws + (size_t)(6 << 20));                 // 128 KiB
  float* sbias = (float*)(ws + (size_t)(6 << 20) + 256 * 256 * 2); // 16 KiB

  ta_wqt_kernel <<<dim3(4, 4),      dim3(256), 0, stream>>>(Wq, WqT);
  ta_kv_kernel  <<<dim3(4, 16, 4),  dim3(256), 0, stream>>>(task, Wk, bk, Wv, bv, k_bf, vTb);
  ta_kw_kernel  <<<dim3(4, 16, 4),  dim3(256), 0, stream>>>(k_bf, WqT, KWs);
  ta_sbias_kernel<<<dim3(16),       dim3(256), 0, stream>>>(k_bf, bq, sbias);
  ta_attn_kernel<<<dim3(256, 16),   dim3(256), 0, stream>>>(image, KWs, vTb, sbias, out);
}